// Round 12
// baseline (301.681 us; speedup 1.0000x reference)
//
#include <hip/hip_runtime.h>
#include <stdint.h>

#define L_SEQ 2048
#define DMODEL 2048
#define NHEADS 16
#define DK 128
#define BATCH 2
#define MROWS (BATCH*L_SEQ)   // 4096

typedef float f32x4 __attribute__((ext_vector_type(4)));
typedef short s16x8 __attribute__((ext_vector_type(8)));
typedef unsigned short u16;
typedef unsigned int u32;

__device__ __forceinline__ u16 f2bf(float f){
  u32 u = __builtin_bit_cast(u32, f);
  u += 0x7fffu + ((u >> 16) & 1u);
  return (u16)(u >> 16);
}
__device__ __forceinline__ float bf2f(u16 h){
  u32 u = ((u32)h) << 16;
  return __builtin_bit_cast(float, u);
}
__device__ __forceinline__ void gload_lds16(const void* g, void* l){
  __builtin_amdgcn_global_load_lds((const __attribute__((address_space(1))) void*)g,
                                   (__attribute__((address_space(3))) void*)l, 16, 0, 0);
}

// ---------------- fp32 -> bf16 convert: all 7 tensors in one launch ----------------
__global__ void k_cvt_all(const float* __restrict__ s0, const float* __restrict__ s1,
                          const float* __restrict__ s2, const float* __restrict__ s3,
                          const float* __restrict__ s4, const float* __restrict__ s5,
                          const float* __restrict__ s6,
                          u16* __restrict__ d0, u16* __restrict__ d1, u16* __restrict__ d2,
                          u16* __restrict__ d3, u16* __restrict__ d4, u16* __restrict__ d5,
                          u16* __restrict__ d6){
  const int XC = MROWS*DMODEL/8;       // 1048576 chunks of 8
  const int WC = DMODEL*DMODEL/8;      // 524288
  const int total = 3*XC + 4*WC;       // 5242880
  int stride = gridDim.x * blockDim.x;
  for (int i = blockIdx.x*blockDim.x + threadIdx.x; i < total; i += stride){
    const float* s; u16* d; int j;
    if (i < XC)        { s=s0; d=d0; j=i; }
    else if (i < 2*XC) { s=s1; d=d1; j=i-XC; }
    else if (i < 3*XC) { s=s2; d=d2; j=i-2*XC; }
    else {
      int k2 = i - 3*XC; int wi = k2 / WC; j = k2 - wi*WC;
      s = wi==0?s3 : wi==1?s4 : wi==2?s5 : s6;
      d = wi==0?d3 : wi==1?d4 : wi==2?d5 : d6;
    }
    const f32x4* sp = (const f32x4*)s + (size_t)j*2;
    f32x4 a = sp[0], b = sp[1];
    s16x8 o;
    o[0]=(short)f2bf(a[0]); o[1]=(short)f2bf(a[1]); o[2]=(short)f2bf(a[2]); o[3]=(short)f2bf(a[3]);
    o[4]=(short)f2bf(b[0]); o[5]=(short)f2bf(b[1]); o[6]=(short)f2bf(b[2]); o[7]=(short)f2bf(b[3]);
    ((s16x8*)d)[j] = o;
  }
}

// ---------------- RoPE cos/sin table (fp32, matches jax fp32 math) ----------------
__global__ void k_tab(float* __restrict__ ct, float* __restrict__ st){
  int idx = blockIdx.x*blockDim.x + threadIdx.x;   // L_SEQ*64 threads
  int l = idx >> 6, i = idx & 63;
  float e = (float)i * (1.0f/64.0f);
  float inv = 1.0f / powf(10000.0f, e);
  float fr = (float)l * inv;
  ct[idx] = cosf(fr);
  st[idx] = sinf(fr);
}

// ---------------- apply RoPE in place on Q and K (one launch) ----------------
__global__ void k_rope2(u16* __restrict__ xq, u16* __restrict__ xk,
                        const float* __restrict__ ct, const float* __restrict__ st){
  int t0 = blockIdx.x*blockDim.x + threadIdx.x;    // 2 * MROWS*128 threads
  u16* x = (t0 & (1<<19)) ? xk : xq;               // MROWS*128 = 524288 = 2^19
  int t = t0 & ((1<<19)-1);
  int i8  = (t & 7) * 8;
  int h   = (t >> 3) & 15;
  int row = t >> 7;
  int l   = row & (L_SEQ-1);
  u16* p = x + (size_t)row*DMODEL + h*DK;
  s16x8 a  = *(s16x8*)(p + i8);
  s16x8 bq = *(s16x8*)(p + 64 + i8);
  const float* cp = ct + l*64 + i8;
  const float* sp = st + l*64 + i8;
  f32x4 c0 = *(const f32x4*)cp, c1 = *(const f32x4*)(cp+4);
  f32x4 s0 = *(const f32x4*)sp, s1 = *(const f32x4*)(sp+4);
  float cc[8] = {c0[0],c0[1],c0[2],c0[3],c1[0],c1[1],c1[2],c1[3]};
  float ss[8] = {s0[0],s0[1],s0[2],s0[3],s1[0],s1[1],s1[2],s1[3]};
  s16x8 y1, y2;
  #pragma unroll
  for (int e=0;e<8;e++){
    float x1 = bf2f((u16)a[e]), x2 = bf2f((u16)bq[e]);
    y1[e] = (short)f2bf(x1*cc[e] - x2*ss[e]);
    y2[e] = (short)f2bf(x1*ss[e] + x2*cc[e]);
  }
  *(s16x8*)(p + i8)      = y1;
  *(s16x8*)(p + 64 + i8) = y2;
}

// ---------------- 256x128-tile deep-pipelined NT GEMM (8 waves, counted vmcnt) ----------------
// C[m][n] = sum_k A[m][k]*B[n][k]. BK=64, double-buffered 96KB LDS, 1 block/CU.
// Per iter: raw barrier -> issue stage(t+1) (6x gload_lds) -> vmcnt(6) -> barrier -> 2x{8 ds_read,16 MFMA}.
__global__ __launch_bounds__(512)
void k_gemm3(const u16* __restrict__ A0, const u16* __restrict__ A1, const u16* __restrict__ A2,
             const u16* __restrict__ B0, const u16* __restrict__ B1, const u16* __restrict__ B2,
             u16* __restrict__ C0, u16* __restrict__ C1, u16* __restrict__ C2){
  __shared__ u16 As[2][256*64];    // 2 x 32KB, rows 128B, XOR swizzled (row&7)<<4
  __shared__ u16 Bs[2][128*64];    // 2 x 16KB
  const int z = blockIdx.z;
  const u16* __restrict__ A  = z==0?A0 : z==1?A1 : A2;
  const u16* __restrict__ Bw = z==0?B0 : z==1?B1 : B2;
  u16* __restrict__ Cb       = z==0?C0 : z==1?C1 : C2;
  const int tid = threadIdx.x, w = tid>>6, l = tid&63;
  const int lg = l>>4, lr = l&15;
  // XCD swizzle: 256 blocks per GEMM -> (lin%8)*32 + lin/8 (bijective)
  const int lin = (int)blockIdx.y*16 + (int)blockIdx.x;
  const int lin2 = (lin&7)*32 + (lin>>3);
  const int bm = (lin2>>4)*256, bn = (lin2&15)*128;
  const int K = DMODEL, N = DMODEL;
  const int wm = (w>>1)*64, wn = (w&1)*64;    // 4M x 2N waves, 64x64 out each
  f32x4 acc[4][4];
  #pragma unroll
  for (int i=0;i<4;i++)
    #pragma unroll
    for (int j=0;j<4;j++) acc[i][j] = (f32x4){0.f,0.f,0.f,0.f};

  auto stage = [&](int t, int buf){
    const int k0 = t*64;
    #pragma unroll
    for (int i=0;i<4;i++){                     // A: 256 rows
      int chunk = i*512 + tid;
      int row = chunk >> 3;
      int cbs = ((chunk&7)<<4) ^ ((row&7)<<4);
      gload_lds16(A + (size_t)(bm+row)*K + k0 + (cbs>>1), (void*)&As[buf][chunk*8]);
    }
    #pragma unroll
    for (int i=0;i<2;i++){                     // B: 128 rows
      int chunk = i*512 + tid;
      int row = chunk >> 3;
      int cbs = ((chunk&7)<<4) ^ ((row&7)<<4);
      gload_lds16(Bw + (size_t)(bn+row)*K + k0 + (cbs>>1), (void*)&Bs[buf][chunk*8]);
    }
  };

  stage(0, 0);
  const int nk = K/64;                         // 32
  for (int t=0; t<nk; t++){
    const int cur = t&1;
    __builtin_amdgcn_s_barrier();              // prev iter's reads of buf[cur^1] complete
    __builtin_amdgcn_sched_barrier(0);
    if (t+1 < nk) stage(t+1, cur^1);           // prefetch: flies for a full iteration
    if (t+1 < nk){ asm volatile("s_waitcnt vmcnt(6)" ::: "memory"); }   // stage(t) landed
    else         { asm volatile("s_waitcnt vmcnt(0)" ::: "memory"); }
    __builtin_amdgcn_sched_barrier(0);
    __builtin_amdgcn_s_barrier();              // all waves' stage(t) visible
    __builtin_amdgcn_sched_barrier(0);
    #pragma unroll
    for (int kc=0; kc<2; kc++){
      s16x8 af[4], bfr[4];
      #pragma unroll
      for (int mi=0; mi<4; mi++){
        int row = wm + mi*16 + lr;
        int off = row*128 + ((kc*64 + lg*16) ^ ((row&7)<<4));
        af[mi] = *(const s16x8*)((const char*)&As[cur][0] + off);
      }
      #pragma unroll
      for (int ni=0; ni<4; ni++){
        int row = wn + ni*16 + lr;
        int off = row*128 + ((kc*64 + lg*16) ^ ((row&7)<<4));
        bfr[ni] = *(const s16x8*)((const char*)&Bs[cur][0] + off);
      }
      __builtin_amdgcn_s_setprio(1);
      #pragma unroll
      for (int mi=0; mi<4; mi++)
        #pragma unroll
        for (int ni=0; ni<4; ni++)
          acc[mi][ni] = __builtin_amdgcn_mfma_f32_16x16x32_bf16(af[mi], bfr[ni], acc[mi][ni], 0,0,0);
      __builtin_amdgcn_s_setprio(0);
    }
  }
  #pragma unroll
  for (int mi=0; mi<4; mi++)
    #pragma unroll
    for (int ni=0; ni<4; ni++)
      #pragma unroll
      for (int r=0; r<4; r++){
        int row = bm + wm + mi*16 + (lg<<2) + r;
        int col = bn + wn + ni*16 + lr;
        Cb[(size_t)row*N + col] = f2bf(acc[mi][ni][r]);
      }
}

// ---------------- output GEMM, same 256x128 pipeline, fp32 out ----------------
__global__ __launch_bounds__(512)
void k_gemm(const u16* __restrict__ A, const u16* __restrict__ Bw,
            float* __restrict__ Cf){
  __shared__ u16 As[2][256*64];
  __shared__ u16 Bs[2][128*64];
  const int tid = threadIdx.x, w = tid>>6, l = tid&63;
  const int lg = l>>4, lr = l&15;
  const int lin = (int)blockIdx.y*16 + (int)blockIdx.x;
  const int lin2 = (lin&7)*32 + (lin>>3);
  const int bm = (lin2>>4)*256, bn = (lin2&15)*128;
  const int K = DMODEL, N = DMODEL;
  const int wm = (w>>1)*64, wn = (w&1)*64;
  f32x4 acc[4][4];
  #pragma unroll
  for (int i=0;i<4;i++)
    #pragma unroll
    for (int j=0;j<4;j++) acc[i][j] = (f32x4){0.f,0.f,0.f,0.f};

  auto stage = [&](int t, int buf){
    const int k0 = t*64;
    #pragma unroll
    for (int i=0;i<4;i++){
      int chunk = i*512 + tid;
      int row = chunk >> 3;
      int cbs = ((chunk&7)<<4) ^ ((row&7)<<4);
      gload_lds16(A + (size_t)(bm+row)*K + k0 + (cbs>>1), (void*)&As[buf][chunk*8]);
    }
    #pragma unroll
    for (int i=0;i<2;i++){
      int chunk = i*512 + tid;
      int row = chunk >> 3;
      int cbs = ((chunk&7)<<4) ^ ((row&7)<<4);
      gload_lds16(Bw + (size_t)(bn+row)*K + k0 + (cbs>>1), (void*)&Bs[buf][chunk*8]);
    }
  };

  stage(0, 0);
  const int nk = K/64;
  for (int t=0; t<nk; t++){
    const int cur = t&1;
    __builtin_amdgcn_s_barrier();
    __builtin_amdgcn_sched_barrier(0);
    if (t+1 < nk) stage(t+1, cur^1);
    if (t+1 < nk){ asm volatile("s_waitcnt vmcnt(6)" ::: "memory"); }
    else         { asm volatile("s_waitcnt vmcnt(0)" ::: "memory"); }
    __builtin_amdgcn_sched_barrier(0);
    __builtin_amdgcn_s_barrier();
    __builtin_amdgcn_sched_barrier(0);
    #pragma unroll
    for (int kc=0; kc<2; kc++){
      s16x8 af[4], bfr[4];
      #pragma unroll
      for (int mi=0; mi<4; mi++){
        int row = wm + mi*16 + lr;
        int off = row*128 + ((kc*64 + lg*16) ^ ((row&7)<<4));
        af[mi] = *(const s16x8*)((const char*)&As[cur][0] + off);
      }
      #pragma unroll
      for (int ni=0; ni<4; ni++){
        int row = wn + ni*16 + lr;
        int off = row*128 + ((kc*64 + lg*16) ^ ((row&7)<<4));
        bfr[ni] = *(const s16x8*)((const char*)&Bs[cur][0] + off);
      }
      __builtin_amdgcn_s_setprio(1);
      #pragma unroll
      for (int mi=0; mi<4; mi++)
        #pragma unroll
        for (int ni=0; ni<4; ni++)
          acc[mi][ni] = __builtin_amdgcn_mfma_f32_16x16x32_bf16(af[mi], bfr[ni], acc[mi][ni], 0,0,0);
      __builtin_amdgcn_s_setprio(0);
    }
  }
  #pragma unroll
  for (int mi=0; mi<4; mi++)
    #pragma unroll
    for (int ni=0; ni<4; ni++)
      #pragma unroll
      for (int r=0; r<4; r++){
        int row = bm + wm + mi*16 + (lg<<2) + r;
        int col = bn + wn + ni*16 + lr;
        Cf[(size_t)row*N + col] = acc[mi][ni][r];
      }
}

// ---------------- causal flash attention (paired q-tiles, XCD-local bh, l-via-MFMA + defer-max) ----
__global__ __launch_bounds__(256)
void k_attn(const u16* __restrict__ Qp, const u16* __restrict__ Kp,
            const u16* __restrict__ Vp, u16* __restrict__ AO){
  __shared__ u16 Ks[2][64*128];    // [k][d], rows 256B, XOR swizzled (row&7)<<4 — double buffered
  __shared__ u16 Vs[128*64];       // [d][k], rows 128B, XOR swizzled ((d>>1)&7)<<4 — single buffer
  __shared__ u16 Ps[4][16*72];     // per-wave P (16 q x 64 k, stride 72 = 144B)
  const int tid = threadIdx.x, w = tid>>6, l = tid&63;
  const int lg = l>>4, lr = l&15;
  const int lin = (int)blockIdx.y * (int)gridDim.x + (int)blockIdx.x;  // 0..511
  const int xcd = lin & 7, s8 = lin >> 3;          // s8: 0..63
  const int bh  = xcd*4 + (s8 >> 4);               // 4 bh per XCD (K/V set fits 4MB L2)
  const int qtp = s8 & 15;                          // q-tile pair index
  const int b = bh>>4, h = bh&15;
  const size_t kvbase = (size_t)(b*L_SEQ)*DMODEL + h*DK;
  const float scale = 0.08838834764831845f;   // 1/sqrt(128)

  u32 vv[2][8];
  s16x8 ones;
  #pragma unroll
  for (int e=0;e<8;e++) ones[e] = (short)0x3F80;   // bf16 1.0 — denominator column

  auto issueK = [&](int j, int buf){
    #pragma unroll
    for (int i=0;i<4;i++){
      int chunk = i*256 + w*64 + l;
      int row = chunk >> 4;                         // 16 chunks (256B) per row
      int cb = ((chunk&15)<<4) ^ ((row&7)<<4);
      const u16* src = Kp + kvbase + (size_t)(j*64 + row)*DMODEL + (cb>>1);
      gload_lds16(src, (void*)&Ks[buf][(i*256 + w*64)*8]);
    }
  };
  auto issueV = [&](int j){
    #pragma unroll
    for (int it=0; it<2; it++){
      int task = it*256 + tid;
      int dp = task & 63, kb = task >> 6;
      const u16* vsrc = Vp + kvbase + (size_t)(j*64 + kb*8)*DMODEL + dp*2;
      #pragma unroll
      for (int e=0;e<8;e++) vv[it][e] = *(const u32*)(vsrc + (size_t)e*DMODEL);
    }
  };
  auto writeV = [&](){
    #pragma unroll
    for (int it=0; it<2; it++){
      int task = it*256 + tid;
      int dp = task & 63, kb = task >> 6;
      int d0 = dp*2;
      s16x8 lo, hi;
      #pragma unroll
      for (int e=0;e<8;e++){ lo[e] = (short)(vv[it][e] & 0xffffu); hi[e] = (short)(vv[it][e] >> 16); }
      int g = ((d0>>1)&7)<<4;
      *(s16x8*)((char*)&Vs[0] + d0*128     + ((kb*16) ^ g)) = lo;
      *(s16x8*)((char*)&Vs[0] + (d0+1)*128 + ((kb*16) ^ g)) = hi;
    }
  };

  for (int half=0; half<2; half++){
    const int qt = half==0 ? qtp : 31-qtp;
    if (half) __syncthreads();

    s16x8 qf[4];
    {
      const u16* qptr = Qp + (size_t)(b*L_SEQ + qt*64 + w*16 + lr)*DMODEL + h*DK + lg*8;
      #pragma unroll
      for (int kc=0; kc<4; kc++) qf[kc] = *(const s16x8*)(qptr + kc*32);
    }
    f32x4 o[9];                                   // o[8] = softmax denominator (V==1 column)
    #pragma unroll
    for (int dt=0; dt<9; dt++) o[dt] = (f32x4){0.f,0.f,0.f,0.f};
    float mrow[4] = {-1e30f,-1e30f,-1e30f,-1e30f};

    issueK(0, 0);
    issueV(0);

    for (int j=0; j<=qt; j++){
      const int cur = j & 1;
      asm volatile("s_waitcnt vmcnt(16)" ::: "memory");   // drain K(j); V(j) stays in flight
      __builtin_amdgcn_sched_barrier(0);
      __builtin_amdgcn_s_barrier();
      __builtin_amdgcn_sched_barrier(0);
      if (j < qt) issueK(j+1, cur^1);

      f32x4 st4[4];
      __builtin_amdgcn_s_setprio(1);
      #pragma unroll
      for (int ni=0; ni<4; ni++){
        f32x4 a = (f32x4){0.f,0.f,0.f,0.f};
        #pragma unroll
        for (int kc=0; kc<4; kc++){
          int row = ni*16 + lr;
          int off = row*256 + ((kc*64 + lg*16) ^ ((row&7)<<4));
          s16x8 kf = *(const s16x8*)((const char*)&Ks[cur][0] + off);
          a = __builtin_amdgcn_mfma_f32_16x16x32_bf16(qf[kc], kf, a, 0,0,0);
        }
        st4[ni] = a;
      }
      __builtin_amdgcn_s_setprio(0);

      // --- mask + scale; coarse wave max for defer check ---
      float sv[4][4];
      float lanemax = -1e30f;
      const bool diag = (j == qt);
      #pragma unroll
      for (int r=0;r<4;r++){
        #pragma unroll
        for (int ni=0;ni<4;ni++){
          float x = st4[ni][r]*scale;
          if (diag){
            int kg = ni*16 + lr;
            int qg = w*16 + lg*4 + r;
            if (kg > qg) x = -1e30f;
          }
          sv[ni][r] = x;
          lanemax = fmaxf(lanemax, x);
        }
      }
      float mmin = fminf(fminf(mrow[0],mrow[1]), fminf(mrow[2],mrow[3]));
      // defer-max (T13): skip rescale when tile max can't exceed running max by >8
      if (!__all(lanemax <= mmin + 8.0f)){
        #pragma unroll
        for (int r=0;r<4;r++){
          float tm = fmaxf(fmaxf(sv[0][r],sv[1][r]), fmaxf(sv[2][r],sv[3][r]));
          #pragma unroll
          for (int msk=1; msk<16; msk<<=1) tm = fmaxf(tm, __shfl_xor(tm, msk, 64));
          float mn = fmaxf(mrow[r], tm);
          float al = __expf(mrow[r]-mn);
          mrow[r] = mn;
          #pragma unroll
          for (int dt=0;dt<9;dt++) o[dt][r] *= al;
        }
      }
      // --- P = exp(s - m); store for PV A-frag (l handled by ones-column MFMA) ---
      #pragma unroll
      for (int r=0;r<4;r++){
        #pragma unroll
        for (int ni=0;ni<4;ni++){
          float p = __expf(sv[ni][r]-mrow[r]);
          Ps[w][(lg*4 + r)*72 + ni*16 + lr] = f2bf(p);
        }
      }
      s16x8 pa[2];
      #pragma unroll
      for (int kc=0;kc<2;kc++) pa[kc] = *(const s16x8*)(&Ps[w][lr*72 + kc*32 + lg*8]);

      if (j < qt){ asm volatile("s_waitcnt vmcnt(4)" ::: "memory"); }
      else       { asm volatile("s_waitcnt vmcnt(0)" ::: "memory"); }
      __builtin_amdgcn_sched_barrier(0);
      writeV();
      if (j < qt) issueV(j+1);
      asm volatile("s_waitcnt lgkmcnt(0)" ::: "memory");
      __builtin_amdgcn_sched_barrier(0);
      __builtin_amdgcn_s_barrier();
      __builtin_amdgcn_sched_barrier(0);

      __builtin_amdgcn_s_setprio(1);
      #pragma unroll
      for (int dt=0;dt<8;dt++){
        #pragma unroll
        for (int kc=0;kc<2;kc++){
          int d = dt*16 + lr;
          int off = d*128 + ((kc*64 + lg*16) ^ (((d>>1)&7)<<4));
          s16x8 vf = *(const s16x8*)((const char*)&Vs[0] + off);
          o[dt] = __builtin_amdgcn_mfma_f32_16x16x32_bf16(pa[kc], vf, o[dt], 0,0,0);
        }
      }
      // denominator: l += P · 1  (register ones-frag, no LDS)
      o[8] = __builtin_amdgcn_mfma_f32_16x16x32_bf16(pa[0], ones, o[8], 0,0,0);
      o[8] = __builtin_amdgcn_mfma_f32_16x16x32_bf16(pa[1], ones, o[8], 0,0,0);
      __builtin_amdgcn_s_setprio(0);
    }

    #pragma unroll
    for (int r=0;r<4;r++){
      float inv = 1.0f / o[8][r];
      size_t rowg = (size_t)(b*L_SEQ + qt*64 + w*16 + lg*4 + r);
      #pragma unroll
      for (int dt=0;dt<8;dt++)
        AO[rowg*DMODEL + h*DK + dt*16 + lr] = f2bf(o[dt][r]*inv);
    }
  }
}

extern "C" void kernel_launch(void* const* d_in, const int* in_sizes, int n_in,
                              void* d_out, int out_size, void* d_ws, size_t ws_size,
                              hipStream_t stream){
  const float* q  = (const float*)d_in[0];
  const float* k  = (const float*)d_in[1];
  const float* v  = (const float*)d_in[2];
  // d_in[3] = mask (causal tril) — structure is fixed, not read
  const float* wq = (const float*)d_in[4];
  const float* wk = (const float*)d_in[5];
  const float* wv = (const float*)d_in[6];
  const float* wo = (const float*)d_in[7];
  (void)in_sizes; (void)n_in; (void)out_size; (void)ws_size;

  const size_t MD = (size_t)MROWS*DMODEL;     // 8388608
  const size_t DD = (size_t)DMODEL*DMODEL;    // 4194304
  char* ws = (char*)d_ws;
  size_t off = 0;
  auto alloc = [&](size_t bytes)->void*{ void* p = ws + off; off += (bytes + 255) & ~(size_t)255; return p; };
  u16* Xq = (u16*)alloc(MD*2);
  u16* Xk = (u16*)alloc(MD*2);
  u16* Xv = (u16*)alloc(MD*2);
  u16* Wq = (u16*)alloc(DD*2);
  u16* Wk = (u16*)alloc(DD*2);
  u16* Wv = (u16*)alloc(DD*2);
  u16* Wo = (u16*)alloc(DD*2);
  u16* Qp = (u16*)alloc(MD*2);
  u16* Kp = (u16*)alloc(MD*2);
  u16* Vp = (u16*)alloc(MD*2);
  float* ct = (float*)alloc((size_t)L_SEQ*64*4);
  float* st = (float*)alloc((size_t)L_SEQ*64*4);
  u16* AO = Xq;   // reuse: Xq dead after Q projection

  k_cvt_all<<<2048,256,0,stream>>>(q, k, v, wq, wk, wv, wo,
                                   Xq, Xk, Xv, Wq, Wk, Wv, Wo);
  k_tab<<<512,256,0,stream>>>(ct, st);

  k_gemm3<<<dim3(16,16,3),512,0,stream>>>(Xq, Xk, Xv, Wq, Wk, Wv, Qp, Kp, Vp);
  k_rope2<<<4096,256,0,stream>>>(Qp, Kp, ct, st);
  k_attn<<<dim3(16,32),256,0,stream>>>(Qp, Kp, Vp, AO);
  k_gemm<<<dim3(16,16),512,0,stream>>>(AO, Wo, (float*)d_out);
}

// Round 13
// 272.403 us; speedup vs baseline: 1.1075x; 1.1075x over previous
//
#include <hip/hip_runtime.h>
#include <stdint.h>

#define L_SEQ 2048
#define DMODEL 2048
#define NHEADS 16
#define DK 128
#define BATCH 2
#define MROWS (BATCH*L_SEQ)   // 4096

typedef float f32x4 __attribute__((ext_vector_type(4)));
typedef short s16x8 __attribute__((ext_vector_type(8)));
typedef unsigned short u16;
typedef unsigned int u32;

__device__ __forceinline__ u16 f2bf(float f){
  u32 u = __builtin_bit_cast(u32, f);
  u += 0x7fffu + ((u >> 16) & 1u);
  return (u16)(u >> 16);
}
__device__ __forceinline__ float bf2f(u16 h){
  u32 u = ((u32)h) << 16;
  return __builtin_bit_cast(float, u);
}
__device__ __forceinline__ void gload_lds16(const void* g, void* l){
  __builtin_amdgcn_global_load_lds((const __attribute__((address_space(1))) void*)g,
                                   (__attribute__((address_space(3))) void*)l, 16, 0, 0);
}

// ---------------- fp32 -> bf16 convert: all 7 tensors in one launch ----------------
__global__ void k_cvt_all(const float* __restrict__ s0, const float* __restrict__ s1,
                          const float* __restrict__ s2, const float* __restrict__ s3,
                          const float* __restrict__ s4, const float* __restrict__ s5,
                          const float* __restrict__ s6,
                          u16* __restrict__ d0, u16* __restrict__ d1, u16* __restrict__ d2,
                          u16* __restrict__ d3, u16* __restrict__ d4, u16* __restrict__ d5,
                          u16* __restrict__ d6){
  const int XC = MROWS*DMODEL/8;       // 1048576 chunks of 8
  const int WC = DMODEL*DMODEL/8;      // 524288
  const int total = 3*XC + 4*WC;       // 5242880
  int stride = gridDim.x * blockDim.x;
  for (int i = blockIdx.x*blockDim.x + threadIdx.x; i < total; i += stride){
    const float* s; u16* d; int j;
    if (i < XC)        { s=s0; d=d0; j=i; }
    else if (i < 2*XC) { s=s1; d=d1; j=i-XC; }
    else if (i < 3*XC) { s=s2; d=d2; j=i-2*XC; }
    else {
      int k2 = i - 3*XC; int wi = k2 / WC; j = k2 - wi*WC;
      s = wi==0?s3 : wi==1?s4 : wi==2?s5 : s6;
      d = wi==0?d3 : wi==1?d4 : wi==2?d5 : d6;
    }
    const f32x4* sp = (const f32x4*)s + (size_t)j*2;
    f32x4 a = sp[0], b = sp[1];
    s16x8 o;
    o[0]=(short)f2bf(a[0]); o[1]=(short)f2bf(a[1]); o[2]=(short)f2bf(a[2]); o[3]=(short)f2bf(a[3]);
    o[4]=(short)f2bf(b[0]); o[5]=(short)f2bf(b[1]); o[6]=(short)f2bf(b[2]); o[7]=(short)f2bf(b[3]);
    ((s16x8*)d)[j] = o;
  }
}

// ---------------- RoPE cos/sin table (fp32, matches jax fp32 math) ----------------
__global__ void k_tab(float* __restrict__ ct, float* __restrict__ st){
  int idx = blockIdx.x*blockDim.x + threadIdx.x;   // L_SEQ*64 threads
  int l = idx >> 6, i = idx & 63;
  float e = (float)i * (1.0f/64.0f);
  float inv = 1.0f / powf(10000.0f, e);
  float fr = (float)l * inv;
  ct[idx] = cosf(fr);
  st[idx] = sinf(fr);
}

// ---------------- fused QKV NT GEMM + RoPE epilogue (z<2) ----------------
// C[m][n] = sum_k A[m][k]*B[n][k]. 128x128 tile, BK=64, 4 waves, XCD swizzle.
// Fragment->column remap so each thread holds RoPE partners (d, d+64):
//   col(ni) = (w&1)*32 + (ni&1)*16 + (ni>>1)*64 + lr   (pairs: ni and ni+2)
__global__ __launch_bounds__(256)
void k_gemm3(const u16* __restrict__ A0, const u16* __restrict__ A1, const u16* __restrict__ A2,
             const u16* __restrict__ B0, const u16* __restrict__ B1, const u16* __restrict__ B2,
             u16* __restrict__ C0, u16* __restrict__ C1, u16* __restrict__ C2,
             const float* __restrict__ ct, const float* __restrict__ st){
  __shared__ u16 As[128*64];
  __shared__ u16 Bs[128*64];
  const int z = blockIdx.z;
  const u16* __restrict__ A  = z==0?A0 : z==1?A1 : A2;
  const u16* __restrict__ Bw = z==0?B0 : z==1?B1 : B2;
  u16* __restrict__ Cb       = z==0?C0 : z==1?C1 : C2;
  const int tid = threadIdx.x, w = tid>>6, l = tid&63;
  const int lg = l>>4, lr = l&15;
  const int lin = (int)blockIdx.y*16 + (int)blockIdx.x;
  const int lin2 = (lin&7)*64 + (lin>>3);
  const int bm = (lin2>>4)*128, bn = (lin2&15)*128;
  const int K = DMODEL, N = DMODEL;
  f32x4 acc[4][4];
  #pragma unroll
  for (int i=0;i<4;i++)
    #pragma unroll
    for (int j=0;j<4;j++) acc[i][j] = (f32x4){0.f,0.f,0.f,0.f};

  const int chunkbase = w*64 + l;
  const int wm = (w>>1)*64, cbase = (w&1)*32;

  for (int k0 = 0; k0 < K; k0 += 64){
    __syncthreads();
    #pragma unroll
    for (int i=0;i<4;i++){
      int chunk = i*256 + chunkbase;
      int row = chunk >> 3;
      int cbs = ((chunk&7)<<4) ^ ((row&7)<<4);
      const u16* ga = A  + (size_t)(bm+row)*K + k0 + (cbs>>1);
      const u16* gb = Bw + (size_t)(bn+row)*K + k0 + (cbs>>1);
      gload_lds16(ga, (void*)&As[(i*256 + w*64)*8]);
      gload_lds16(gb, (void*)&Bs[(i*256 + w*64)*8]);
    }
    __syncthreads();
    #pragma unroll
    for (int kc=0; kc<2; kc++){
      s16x8 af[4], bfr[4];
      #pragma unroll
      for (int mi=0; mi<4; mi++){
        int row = wm + mi*16 + lr;
        int off = row*128 + ((kc*64 + lg*16) ^ ((row&7)<<4));
        af[mi] = *(const s16x8*)((const char*)As + off);
      }
      #pragma unroll
      for (int ni=0; ni<4; ni++){
        int row = cbase + (ni&1)*16 + (ni>>1)*64 + lr;   // = output col (RoPE-pair layout)
        int off = row*128 + ((kc*64 + lg*16) ^ ((row&7)<<4));
        bfr[ni] = *(const s16x8*)((const char*)Bs + off);
      }
      #pragma unroll
      for (int mi=0; mi<4; mi++)
        #pragma unroll
        for (int ni=0; ni<4; ni++)
          acc[mi][ni] = __builtin_amdgcn_mfma_f32_16x16x32_bf16(af[mi], bfr[ni], acc[mi][ni], 0,0,0);
    }
  }
  if (z < 2){
    // fused RoPE on fp32 accumulators: pairs (ni, ni+2) hold (d, d+64), d in [0,64)
    #pragma unroll
    for (int mi=0; mi<4; mi++)
      #pragma unroll
      for (int r=0; r<4; r++){
        int row = bm + wm + mi*16 + (lg<<2) + r;
        int lq = row & (L_SEQ-1);
        #pragma unroll
        for (int p=0; p<2; p++){
          int d = cbase + p*16 + lr;
          float cs = ct[lq*64 + d], sn = st[lq*64 + d];
          float x1 = acc[mi][p][r], x2 = acc[mi][p+2][r];
          Cb[(size_t)row*N + bn + d]      = f2bf(x1*cs - x2*sn);
          Cb[(size_t)row*N + bn + d + 64] = f2bf(x1*sn + x2*cs);
        }
      }
  } else {
    #pragma unroll
    for (int mi=0; mi<4; mi++)
      #pragma unroll
      for (int ni=0; ni<4; ni++)
        #pragma unroll
        for (int r=0; r<4; r++){
          int row = bm + wm + mi*16 + (lg<<2) + r;
          int col = bn + cbase + (ni&1)*16 + (ni>>1)*64 + lr;
          Cb[(size_t)row*N + col] = f2bf(acc[mi][ni][r]);
        }
  }
}

// ---------------- output NT GEMM (fp32 out) ----------------
__global__ __launch_bounds__(256)
void k_gemm(const u16* __restrict__ A, const u16* __restrict__ Bw,
            float* __restrict__ Cf){
  __shared__ u16 As[128*64];
  __shared__ u16 Bs[128*64];
  const int tid = threadIdx.x, w = tid>>6, l = tid&63;
  const int lg = l>>4, lr = l&15;
  const int lin = (int)blockIdx.y*16 + (int)blockIdx.x;
  const int lin2 = (lin&7)*64 + (lin>>3);
  const int bm = (lin2>>4)*128, bn = (lin2&15)*128;
  const int K = DMODEL, N = DMODEL;
  f32x4 acc[4][4];
  #pragma unroll
  for (int i=0;i<4;i++)
    #pragma unroll
    for (int j=0;j<4;j++) acc[i][j] = (f32x4){0.f,0.f,0.f,0.f};

  const int chunkbase = w*64 + l;
  const int wm = (w>>1)*64, wn = (w&1)*64;

  for (int k0 = 0; k0 < K; k0 += 64){
    __syncthreads();
    #pragma unroll
    for (int i=0;i<4;i++){
      int chunk = i*256 + chunkbase;
      int row = chunk >> 3;
      int cbs = ((chunk&7)<<4) ^ ((row&7)<<4);
      const u16* ga = A  + (size_t)(bm+row)*K + k0 + (cbs>>1);
      const u16* gb = Bw + (size_t)(bn+row)*K + k0 + (cbs>>1);
      gload_lds16(ga, (void*)&As[(i*256 + w*64)*8]);
      gload_lds16(gb, (void*)&Bs[(i*256 + w*64)*8]);
    }
    __syncthreads();
    #pragma unroll
    for (int kc=0; kc<2; kc++){
      s16x8 af[4], bfr[4];
      #pragma unroll
      for (int mi=0; mi<4; mi++){
        int row = wm + mi*16 + lr;
        int off = row*128 + ((kc*64 + lg*16) ^ ((row&7)<<4));
        af[mi] = *(const s16x8*)((const char*)As + off);
      }
      #pragma unroll
      for (int ni=0; ni<4; ni++){
        int row = wn + ni*16 + lr;
        int off = row*128 + ((kc*64 + lg*16) ^ ((row&7)<<4));
        bfr[ni] = *(const s16x8*)((const char*)Bs + off);
      }
      #pragma unroll
      for (int mi=0; mi<4; mi++)
        #pragma unroll
        for (int ni=0; ni<4; ni++)
          acc[mi][ni] = __builtin_amdgcn_mfma_f32_16x16x32_bf16(af[mi], bfr[ni], acc[mi][ni], 0,0,0);
    }
  }
  #pragma unroll
  for (int mi=0; mi<4; mi++)
    #pragma unroll
    for (int ni=0; ni<4; ni++)
      #pragma unroll
      for (int r=0; r<4; r++){
        int row = bm + wm + mi*16 + (lg<<2) + r;
        int col = bn + wn + ni*16 + lr;
        Cf[(size_t)row*N + col] = acc[mi][ni][r];
      }
}

// ---------------- causal flash attention (paired q-tiles, XCD-local bh, l-via-MFMA + defer-max) ----
__global__ __launch_bounds__(256)
void k_attn(const u16* __restrict__ Qp, const u16* __restrict__ Kp,
            const u16* __restrict__ Vp, u16* __restrict__ AO){
  __shared__ u16 Ks[2][64*128];    // [k][d], rows 256B, XOR swizzled (row&7)<<4 — double buffered
  __shared__ u16 Vs[128*64];       // [d][k], rows 128B, XOR swizzled ((d>>1)&7)<<4 — single buffer
  __shared__ u16 Ps[4][16*72];     // per-wave P (16 q x 64 k, stride 72 = 144B)
  const int tid = threadIdx.x, w = tid>>6, l = tid&63;
  const int lg = l>>4, lr = l&15;
  const int lin = (int)blockIdx.y * (int)gridDim.x + (int)blockIdx.x;  // 0..511
  const int xcd = lin & 7, s8 = lin >> 3;          // s8: 0..63
  const int bh  = xcd*4 + (s8 >> 4);               // 4 bh per XCD (K/V set fits 4MB L2)
  const int qtp = s8 & 15;                          // q-tile pair index
  const int b = bh>>4, h = bh&15;
  const size_t kvbase = (size_t)(b*L_SEQ)*DMODEL + h*DK;
  const float scale = 0.08838834764831845f;   // 1/sqrt(128)

  u32 vv[2][8];
  s16x8 ones;
  #pragma unroll
  for (int e=0;e<8;e++) ones[e] = (short)0x3F80;   // bf16 1.0 — denominator column

  auto issueK = [&](int j, int buf){
    #pragma unroll
    for (int i=0;i<4;i++){
      int chunk = i*256 + w*64 + l;
      int row = chunk >> 4;                         // 16 chunks (256B) per row
      int cb = ((chunk&15)<<4) ^ ((row&7)<<4);
      const u16* src = Kp + kvbase + (size_t)(j*64 + row)*DMODEL + (cb>>1);
      gload_lds16(src, (void*)&Ks[buf][(i*256 + w*64)*8]);
    }
  };
  auto issueV = [&](int j){
    #pragma unroll
    for (int it=0; it<2; it++){
      int task = it*256 + tid;
      int dp = task & 63, kb = task >> 6;
      const u16* vsrc = Vp + kvbase + (size_t)(j*64 + kb*8)*DMODEL + dp*2;
      #pragma unroll
      for (int e=0;e<8;e++) vv[it][e] = *(const u32*)(vsrc + (size_t)e*DMODEL);
    }
  };
  auto writeV = [&](){
    #pragma unroll
    for (int it=0; it<2; it++){
      int task = it*256 + tid;
      int dp = task & 63, kb = task >> 6;
      int d0 = dp*2;
      s16x8 lo, hi;
      #pragma unroll
      for (int e=0;e<8;e++){ lo[e] = (short)(vv[it][e] & 0xffffu); hi[e] = (short)(vv[it][e] >> 16); }
      int g = ((d0>>1)&7)<<4;
      *(s16x8*)((char*)&Vs[0] + d0*128     + ((kb*16) ^ g)) = lo;
      *(s16x8*)((char*)&Vs[0] + (d0+1)*128 + ((kb*16) ^ g)) = hi;
    }
  };

  for (int half=0; half<2; half++){
    const int qt = half==0 ? qtp : 31-qtp;
    if (half) __syncthreads();

    s16x8 qf[4];
    {
      const u16* qptr = Qp + (size_t)(b*L_SEQ + qt*64 + w*16 + lr)*DMODEL + h*DK + lg*8;
      #pragma unroll
      for (int kc=0; kc<4; kc++) qf[kc] = *(const s16x8*)(qptr + kc*32);
    }
    f32x4 o[9];                                   // o[8] = softmax denominator (V==1 column)
    #pragma unroll
    for (int dt=0; dt<9; dt++) o[dt] = (f32x4){0.f,0.f,0.f,0.f};
    float mrow[4] = {-1e30f,-1e30f,-1e30f,-1e30f};

    issueK(0, 0);
    issueV(0);

    for (int j=0; j<=qt; j++){
      const int cur = j & 1;
      asm volatile("s_waitcnt vmcnt(16)" ::: "memory");   // drain K(j); V(j) stays in flight
      __builtin_amdgcn_sched_barrier(0);
      __builtin_amdgcn_s_barrier();
      __builtin_amdgcn_sched_barrier(0);
      if (j < qt) issueK(j+1, cur^1);

      f32x4 st4[4];
      __builtin_amdgcn_s_setprio(1);
      #pragma unroll
      for (int ni=0; ni<4; ni++){
        f32x4 a = (f32x4){0.f,0.f,0.f,0.f};
        #pragma unroll
        for (int kc=0; kc<4; kc++){
          int row = ni*16 + lr;
          int off = row*256 + ((kc*64 + lg*16) ^ ((row&7)<<4));
          s16x8 kf = *(const s16x8*)((const char*)&Ks[cur][0] + off);
          a = __builtin_amdgcn_mfma_f32_16x16x32_bf16(qf[kc], kf, a, 0,0,0);
        }
        st4[ni] = a;
      }
      __builtin_amdgcn_s_setprio(0);

      // --- mask + scale; coarse wave max for defer check ---
      float sv[4][4];
      float lanemax = -1e30f;
      const bool diag = (j == qt);
      #pragma unroll
      for (int r=0;r<4;r++){
        #pragma unroll
        for (int ni=0;ni<4;ni++){
          float x = st4[ni][r]*scale;
          if (diag){
            int kg = ni*16 + lr;
            int qg = w*16 + lg*4 + r;
            if (kg > qg) x = -1e30f;
          }
          sv[ni][r] = x;
          lanemax = fmaxf(lanemax, x);
        }
      }
      float mmin = fminf(fminf(mrow[0],mrow[1]), fminf(mrow[2],mrow[3]));
      // defer-max (T13): skip rescale when tile max can't exceed running max by >8
      if (!__all(lanemax <= mmin + 8.0f)){
        #pragma unroll
        for (int r=0;r<4;r++){
          float tm = fmaxf(fmaxf(sv[0][r],sv[1][r]), fmaxf(sv[2][r],sv[3][r]));
          #pragma unroll
          for (int msk=1; msk<16; msk<<=1) tm = fmaxf(tm, __shfl_xor(tm, msk, 64));
          float mn = fmaxf(mrow[r], tm);
          float al = __expf(mrow[r]-mn);
          mrow[r] = mn;
          #pragma unroll
          for (int dt=0;dt<9;dt++) o[dt][r] *= al;
        }
      }
      // --- P = exp(s - m); store for PV A-frag (l handled by ones-column MFMA) ---
      #pragma unroll
      for (int r=0;r<4;r++){
        #pragma unroll
        for (int ni=0;ni<4;ni++){
          float p = __expf(sv[ni][r]-mrow[r]);
          Ps[w][(lg*4 + r)*72 + ni*16 + lr] = f2bf(p);
        }
      }
      s16x8 pa[2];
      #pragma unroll
      for (int kc=0;kc<2;kc++) pa[kc] = *(const s16x8*)(&Ps[w][lr*72 + kc*32 + lg*8]);

      if (j < qt){ asm volatile("s_waitcnt vmcnt(4)" ::: "memory"); }
      else       { asm volatile("s_waitcnt vmcnt(0)" ::: "memory"); }
      __builtin_amdgcn_sched_barrier(0);
      writeV();
      if (j < qt) issueV(j+1);
      asm volatile("s_waitcnt lgkmcnt(0)" ::: "memory");
      __builtin_amdgcn_sched_barrier(0);
      __builtin_amdgcn_s_barrier();
      __builtin_amdgcn_sched_barrier(0);

      __builtin_amdgcn_s_setprio(1);
      #pragma unroll
      for (int dt=0;dt<8;dt++){
        #pragma unroll
        for (int kc=0;kc<2;kc++){
          int d = dt*16 + lr;
          int off = d*128 + ((kc*64 + lg*16) ^ (((d>>1)&7)<<4));
          s16x8 vf = *(const s16x8*)((const char*)&Vs[0] + off);
          o[dt] = __builtin_amdgcn_mfma_f32_16x16x32_bf16(pa[kc], vf, o[dt], 0,0,0);
        }
      }
      // denominator: l += P · 1  (register ones-frag, no LDS)
      o[8] = __builtin_amdgcn_mfma_f32_16x16x32_bf16(pa[0], ones, o[8], 0,0,0);
      o[8] = __builtin_amdgcn_mfma_f32_16x16x32_bf16(pa[1], ones, o[8], 0,0,0);
      __builtin_amdgcn_s_setprio(0);
    }

    #pragma unroll
    for (int r=0;r<4;r++){
      float inv = 1.0f / o[8][r];
      size_t rowg = (size_t)(b*L_SEQ + qt*64 + w*16 + lg*4 + r);
      #pragma unroll
      for (int dt=0;dt<8;dt++)
        AO[rowg*DMODEL + h*DK + dt*16 + lr] = f2bf(o[dt][r]*inv);
    }
  }
}

extern "C" void kernel_launch(void* const* d_in, const int* in_sizes, int n_in,
                              void* d_out, int out_size, void* d_ws, size_t ws_size,
                              hipStream_t stream){
  const float* q  = (const float*)d_in[0];
  const float* k  = (const float*)d_in[1];
  const float* v  = (const float*)d_in[2];
  // d_in[3] = mask (causal tril) — structure is fixed, not read
  const float* wq = (const float*)d_in[4];
  const float* wk = (const float*)d_in[5];
  const float* wv = (const float*)d_in[6];
  const float* wo = (const float*)d_in[7];
  (void)in_sizes; (void)n_in; (void)out_size; (void)ws_size;

  const size_t MD = (size_t)MROWS*DMODEL;     // 8388608
  const size_t DD = (size_t)DMODEL*DMODEL;    // 4194304
  char* ws = (char*)d_ws;
  size_t off = 0;
  auto alloc = [&](size_t bytes)->void*{ void* p = ws + off; off += (bytes + 255) & ~(size_t)255; return p; };
  u16* Xq = (u16*)alloc(MD*2);
  u16* Xk = (u16*)alloc(MD*2);
  u16* Xv = (u16*)alloc(MD*2);
  u16* Wq = (u16*)alloc(DD*2);
  u16* Wk = (u16*)alloc(DD*2);
  u16* Wv = (u16*)alloc(DD*2);
  u16* Wo = (u16*)alloc(DD*2);
  u16* Qp = (u16*)alloc(MD*2);
  u16* Kp = (u16*)alloc(MD*2);
  u16* Vp = (u16*)alloc(MD*2);
  float* ct = (float*)alloc((size_t)L_SEQ*64*4);
  float* st = (float*)alloc((size_t)L_SEQ*64*4);
  u16* AO = Xq;   // reuse: Xq dead after Q projection

  k_cvt_all<<<2048,256,0,stream>>>(q, k, v, wq, wk, wv, wo,
                                   Xq, Xk, Xv, Wq, Wk, Wv, Wo);
  k_tab<<<512,256,0,stream>>>(ct, st);

  k_gemm3<<<dim3(16,32,3),256,0,stream>>>(Xq, Xk, Xv, Wq, Wk, Wv, Qp, Kp, Vp, ct, st);
  k_attn<<<dim3(16,32),256,0,stream>>>(Qp, Kp, Vp, AO);
  k_gemm<<<dim3(16,32),256,0,stream>>>(AO, Wo, (float*)d_out);
}